// Round 3
// baseline (656.783 us; speedup 1.0000x reference)
//
#include <hip/hip_runtime.h>
#include <math.h>

// (B,T,C)=(4,4096,1024), 16 heads x 64, window 256, rope base 1e4.
#define T_SEQ 4096
#define CDIM  1024
#define WIN   256

// log2(10000)/32 — inv_freq[pi] = 2^(-pi * ROPE_C)
#define ROPE_C 0.415241012f
// 0.125 * log2(e): softmax in exp2 domain
#define SCALE_LOG2E 0.1803368801f

typedef __attribute__((ext_vector_type(8))) short short8;
typedef __attribute__((ext_vector_type(4))) float float4v;

__device__ __forceinline__ unsigned int f2bf(float f) {
  unsigned int u = __float_as_uint(f);
  u += 0x7fffu + ((u >> 16) & 1u);
  return u >> 16;
}

// async global->LDS, 16B per lane. LDS dest must be linear (wave base + lane*16).
__device__ __forceinline__ void gload16(const unsigned short* g, unsigned short* l) {
  __builtin_amdgcn_global_load_lds(
      (__attribute__((address_space(1))) void*)g,
      (__attribute__((address_space(3))) void*)l, 16, 0, 0);
}

// ---------------------------------------------------------------------------
// RoPE table: tab[t*32+pi] = {cos(t*inv[pi]), sin(t*inv[pi])}, 4096x32, 1 MiB.
// ---------------------------------------------------------------------------
__global__ __launch_bounds__(256)
void rope_tab(float2* __restrict__ tab) {
  const int i = blockIdx.x * 256 + threadIdx.x;   // 0..131071
  const int tpos = i >> 5, pi = i & 31;
  const float ang = (float)tpos * exp2f(-(float)pi * ROPE_C);
  tab[i] = make_float2(cosf(ang), sinf(ang));
}

// ---------------------------------------------------------------------------
// x fp32 -> bf16, 8 elems/thread.
// ---------------------------------------------------------------------------
__global__ __launch_bounds__(256)
void cvt_f32_bf16(const float* __restrict__ src, unsigned short* __restrict__ dst) {
  const long i = ((long)blockIdx.x * 256 + threadIdx.x) * 8;
  float4 u0 = *(const float4*)(src + i);
  float4 u1 = *(const float4*)(src + i + 4);
  uint4 pk;
  pk.x = f2bf(u0.x) | (f2bf(u0.y) << 16);
  pk.y = f2bf(u0.z) | (f2bf(u0.w) << 16);
  pk.z = f2bf(u1.x) | (f2bf(u1.y) << 16);
  pk.w = f2bf(u1.z) | (f2bf(u1.w) << 16);
  *(uint4*)(dst + i) = pk;
}

// ---------------------------------------------------------------------------
// W fp32 [K][N] row-major -> W^T bf16 [N][K] linear.
// ---------------------------------------------------------------------------
__global__ __launch_bounds__(256)
void transpose_cvt(const float* __restrict__ W, unsigned short* __restrict__ dst,
                   int K, int N) {
  __shared__ float tile[32][33];
  const int tid = threadIdx.x;
  const int ktile = blockIdx.y * 32, ntile = blockIdx.x * 32;
  const int kl = tid >> 3, nl4 = (tid & 7) * 4;
  float4 v = *(const float4*)&W[(size_t)(ktile + kl) * N + ntile + nl4];
  tile[nl4 + 0][kl] = v.x;
  tile[nl4 + 1][kl] = v.y;
  tile[nl4 + 2][kl] = v.z;
  tile[nl4 + 3][kl] = v.w;
  __syncthreads();
  const int nl = tid >> 3, kl4 = (tid & 7) * 4;
  uint2 pk;
  pk.x = f2bf(tile[nl][kl4 + 0]) | (f2bf(tile[nl][kl4 + 1]) << 16);
  pk.y = f2bf(tile[nl][kl4 + 2]) | (f2bf(tile[nl][kl4 + 3]) << 16);
  long i = (long)(ntile + nl) * K + ktile + kl4;
  *(uint2*)(dst + i) = pk;
}

// ---------------------------------------------------------------------------
// Pure-bf16 MFMA GEMM, m97 structure: C = A(bf16 [M][K]) @ Bt(bf16 [N][K])^T
// + bias. 128x128 block, 4 waves, 16x16x32 mfma, BK=32. LDS = 16 KiB TOTAL
// (occupancy-critical: R2's 32 KiB halved residency and regressed 15%).
// mode=1: RoPE via table gather; bf16 C-tile staged through the SAME 16 KiB
// in two 64-row passes -> 16B coalesced stores (256B/row segments).
// mode=0: fp32 direct stores.
// ---------------------------------------------------------------------------
__global__ __launch_bounds__(256)
void gemm_bf16(const unsigned short* __restrict__ A,
               const unsigned short* __restrict__ Bt,
               const float* __restrict__ bias,
               const float2* __restrict__ ropetab,
               void* __restrict__ Cp, int ldc, int K, int mode) {
  __shared__ unsigned short smem[64 * 128];    // 16 KiB total
  unsigned short* As = smem;                   // [0, 4096) main loop
  unsigned short* Bs = smem + 128 * 32;        // [4096, 8192) main loop
  const int t = threadIdx.x;
  const int row0 = blockIdx.y * 128, col0 = blockIdx.x * 128;
  const int lane = t & 63, wave = t >> 6;
  const int wm = (wave >> 1) * 64, wn = (wave & 1) * 64;
  const int l15 = lane & 15, quad = lane >> 4;

  // staging map: thread t covers LDS elems [t*8, t*8+8) (+2048 for pass 1)
  // -> tile row sr = t>>2 (+64), LDS chunk t&3. Source chunk = (t&3)^((sr>>1)&3).
  const int sr = t >> 2;
  const int sc = (t & 3) ^ ((sr >> 1) & 3);
  const unsigned short* a0 = A + (size_t)(row0 + sr) * K + sc * 8;
  const unsigned short* b0 = Bt + (size_t)(col0 + sr) * K + sc * 8;
  unsigned short* la = &As[t * 8];
  unsigned short* lb = &Bs[t * 8];

  float4v acc[4][4];
#pragma unroll
  for (int i = 0; i < 4; ++i)
#pragma unroll
    for (int j = 0; j < 4; ++j) acc[i][j] = (float4v){0.f, 0.f, 0.f, 0.f};

  for (int k0 = 0; k0 < K; k0 += 32) {
    __syncthreads();                      // all waves done reading prev tile
    gload16(a0 + k0, la);
    gload16(a0 + (size_t)64 * K + k0, la + 2048);
    gload16(b0 + k0, lb);
    gload16(b0 + (size_t)64 * K + k0, lb + 2048);
    asm volatile("s_waitcnt vmcnt(0)" ::: "memory");
    __syncthreads();                      // tile ready for everyone

    short8 af[4], bfr[4];
#pragma unroll
    for (int mt = 0; mt < 4; ++mt) {
      const int r = wm + mt * 16 + l15;
      af[mt] = *(const short8*)&As[r * 32 + ((quad ^ ((r >> 1) & 3)) * 8)];
    }
#pragma unroll
    for (int nt = 0; nt < 4; ++nt) {
      const int r = wn + nt * 16 + l15;
      bfr[nt] = *(const short8*)&Bs[r * 32 + ((quad ^ ((r >> 1) & 3)) * 8)];
    }
#pragma unroll
    for (int mt = 0; mt < 4; ++mt)
#pragma unroll
      for (int nt = 0; nt < 4; ++nt)
        acc[mt][nt] = __builtin_amdgcn_mfma_f32_16x16x32_bf16(af[mt], bfr[nt],
                                                              acc[mt][nt], 0, 0, 0);
  }

  if (mode) {
    // ---- bf16 epilogue: rope table, 2x 64-row LDS passes, 16B stores ----
    const bool rope = (col0 < 2 * CDIM);   // uniform per block
    unsigned short* co = (unsigned short*)Cp;
#pragma unroll
    for (int p = 0; p < 2; ++p) {
      __syncthreads();                     // LDS free (main loop / prev store)
      if ((wave >> 1) == p) {              // wave-uniform branch
#pragma unroll
        for (int nt = 0; nt < 4; ++nt) {
          const int col_l = wn + nt * 16 + l15;
          const int col = col0 + col_l;
          const float bb = bias[col];
          const int pi = (col & 63) >> 1;
          const float sgn = (col & 1) ? 1.f : -1.f;
#pragma unroll
          for (int mt = 0; mt < 4; ++mt) {
#pragma unroll
            for (int r = 0; r < 4; ++r) {
              const int rlh = mt * 16 + quad * 4 + r;   // local row 0..63
              const int row = row0 + p * 64 + rlh;
              float v = acc[mt][nt][r] + bb;
              const float vp = __shfl_xor(v, 1);
              if (rope) {
                const float2 cs = ropetab[(size_t)(row & (T_SEQ - 1)) * 32 + pi];
                v = v * cs.x + sgn * vp * cs.y;
              }
              const float v2 = __shfl_xor(v, 1);   // partner's final value
              if (!(l15 & 1)) {
                const int ch = col_l >> 3;          // logical 16B chunk 0..15
                const int phys = ch ^ (rlh & 15);   // bank-spread involution
                *(unsigned int*)&smem[rlh * 128 + phys * 8 + (col_l & 7)] =
                    f2bf(v) | (f2bf(v2) << 16);
              }
            }
          }
        }
      }
      __syncthreads();
      // all 256 threads store 64 rows x 128 cols (4x 16B each)
      const int rr = t >> 2;
      const int cb = (t & 3) * 4;
#pragma unroll
      for (int c = 0; c < 4; ++c) {
        const int lc = cb + c;
        uint4 val = *(const uint4*)&smem[rr * 128 + ((lc ^ (rr & 15)) * 8)];
        *(uint4*)(co + (size_t)(row0 + p * 64 + rr) * ldc + col0 + lc * 8) = val;
      }
    }
  } else {
    // ---- fp32 epilogue (output GEMM): direct stores ----
    float* co = (float*)Cp;
#pragma unroll
    for (int nt = 0; nt < 4; ++nt) {
      const int col = col0 + wn + nt * 16 + l15;
      const float bb = bias[col];
#pragma unroll
      for (int mt = 0; mt < 4; ++mt) {
#pragma unroll
        for (int r = 0; r < 4; ++r) {
          const int row = row0 + wm + mt * 16 + quad * 4 + r;
          co[(size_t)row * ldc + col] = acc[mt][nt][r] + bb;
        }
      }
    }
  }
}

// ---------------------------------------------------------------------------
// MFMA flash attention on bf16 qkv (unchanged from R1).
// ---------------------------------------------------------------------------
__global__ __launch_bounds__(256, 2)
void attn_mfma(const unsigned short* __restrict__ qkv, unsigned short* __restrict__ Y) {
  __shared__ unsigned short Ks[128 * 64];   // [key][d], 16 KiB
  __shared__ unsigned short Vt[64 * 128];   // [d][key], 16 KiB
  __shared__ unsigned short Ps[4][64 * 32]; // per-wave P chunk, 16 KiB

  const int w = blockIdx.x, h = blockIdx.y, b = blockIdx.z;
  const int t = threadIdx.x;
  const int lane = t & 63, wv = t >> 6;
  const int l15 = lane & 15, quad = lane >> 4;
  const int t0 = w * WIN;
  const size_t base = ((size_t)b * T_SEQ + t0) * 3072;

  // ---- Q A-frags: direct bf16 16B loads ----
  short8 qf[4][2];
#pragma unroll
  for (int mt = 0; mt < 4; ++mt) {
    const unsigned short* qp = qkv + base + (size_t)(wv * 64 + mt * 16 + l15) * 3072 + h * 64;
#pragma unroll
    for (int ks = 0; ks < 2; ++ks)
      qf[mt][ks] = *(const short8*)(qp + ks * 32 + quad * 8);
  }

  float4v accy[4][4];
#pragma unroll
  for (int i = 0; i < 4; ++i)
#pragma unroll
    for (int j = 0; j < 4; ++j) accy[i][j] = (float4v){0.f, 0.f, 0.f, 0.f};
  float m_[4][4], l_[4][4];
#pragma unroll
  for (int i = 0; i < 4; ++i)
#pragma unroll
    for (int j = 0; j < 4; ++j) { m_[i][j] = -3.0e38f; l_[i][j] = 0.f; }

  for (int half = 0; half < 2; ++half) {
    if (half) __syncthreads();   // all waves done reading previous half
    // ---- stage K half via global_load_lds ----
    {
      const int kr = t >> 3, kc = t & 7;
      const unsigned short* kp = qkv + base + (size_t)(half * 128 + kr) * 3072 + 1024 +
                                 h * 64 + ((kc ^ (kr & 7)) * 8);
      unsigned short* lp = &Ks[t * 8];
#pragma unroll
      for (int p = 0; p < 4; ++p)
        gload16(kp + (size_t)p * 32 * 3072, lp + p * 2048);
    }
    // ---- stage V^T half ----
    {
      const int kpair = 2 * (t & 63);
      const int d0 = (t >> 6) * 16;
      const unsigned short* v0 = qkv + base + (size_t)(half * 128 + kpair) * 3072 + 2048 +
                                 h * 64 + d0;
      const unsigned short* v1 = v0 + 3072;
      short8 a0[2], a1[2];
#pragma unroll
      for (int j = 0; j < 2; ++j) {
        a0[j] = *(const short8*)(v0 + j * 8);
        a1[j] = *(const short8*)(v1 + j * 8);
      }
      const int c = kpair >> 3;
#pragma unroll
      for (int j = 0; j < 2; ++j)
#pragma unroll
        for (int e = 0; e < 8; ++e) {
          const int d = d0 + 8 * j + e;
          const unsigned int pk = (unsigned int)(unsigned short)a0[j][e] |
                                  ((unsigned int)(unsigned short)a1[j][e] << 16);
          *(unsigned int*)&Vt[d * 128 + ((c ^ (d & 7)) * 8) + (kpair & 7)] = pk;
        }
    }
    asm volatile("s_waitcnt vmcnt(0)" ::: "memory");
    __syncthreads();

    for (int kc = 0; kc < 4; ++kc) {   // 32-key chunks within half
      short8 kf[2][2];
#pragma unroll
      for (int nt = 0; nt < 2; ++nt)
#pragma unroll
        for (int ks = 0; ks < 2; ++ks) {
          const int r = kc * 32 + nt * 16 + l15;
          const int c = ks * 4 + quad;
          kf[nt][ks] = *(const short8*)&Ks[r * 64 + ((c ^ (l15 & 7)) * 8)];
        }
      float4v s_[4][2];
#pragma unroll
      for (int mt = 0; mt < 4; ++mt)
#pragma unroll
        for (int nt = 0; nt < 2; ++nt) {
          s_[mt][nt] = __builtin_amdgcn_mfma_f32_16x16x32_bf16(
              qf[mt][0], kf[nt][0], (float4v){0.f, 0.f, 0.f, 0.f}, 0, 0, 0);
          s_[mt][nt] = __builtin_amdgcn_mfma_f32_16x16x32_bf16(
              qf[mt][1], kf[nt][1], s_[mt][nt], 0, 0, 0);
        }
      // ---- online softmax + P write ----
#pragma unroll
      for (int mt = 0; mt < 4; ++mt) {
#pragma unroll
        for (int reg = 0; reg < 4; ++reg) {
          float s0 = s_[mt][0][reg] * SCALE_LOG2E;
          float s1 = s_[mt][1][reg] * SCALE_LOG2E;
          float mx = fmaxf(s0, s1);
          mx = fmaxf(mx, __shfl_xor(mx, 1));
          mx = fmaxf(mx, __shfl_xor(mx, 2));
          mx = fmaxf(mx, __shfl_xor(mx, 4));
          mx = fmaxf(mx, __shfl_xor(mx, 8));
          const float mn = fmaxf(m_[mt][reg], mx);
          const float al = exp2f(m_[mt][reg] - mn);
          const float p0 = exp2f(s0 - mn);
          const float p1 = exp2f(s1 - mn);
          float ps = p0 + p1;
          ps += __shfl_xor(ps, 1);
          ps += __shfl_xor(ps, 2);
          ps += __shfl_xor(ps, 4);
          ps += __shfl_xor(ps, 8);
          l_[mt][reg] = l_[mt][reg] * al + ps;
          m_[mt][reg] = mn;
#pragma unroll
          for (int dt = 0; dt < 4; ++dt) accy[mt][dt][reg] *= al;
          const float q0 = __shfl_xor(p0, 1);
          const float q1 = __shfl_xor(p1, 1);
          const unsigned int w0 = f2bf(p0) | (f2bf(q0) << 16);
          const unsigned int w1 = f2bf(p1) | (f2bf(q1) << 16);
          if (!(l15 & 1)) {
            const int row = mt * 16 + quad * 4 + reg;
            const int ca = (0 + (l15 >> 3)) ^ (row & 3);
            const int cb = (2 + (l15 >> 3)) ^ (row & 3);
            *(unsigned int*)&Ps[wv][row * 32 + ca * 8 + (l15 & 7)] = w0;
            *(unsigned int*)&Ps[wv][row * 32 + cb * 8 + (l15 & 7)] = w1;
          }
        }
      }
      // ---- P A-frags + V^T B-frags, y += P @ V ----
      short8 pf[4], vf[4];
#pragma unroll
      for (int mt = 0; mt < 4; ++mt) {
        const int row = mt * 16 + l15;
        pf[mt] = *(const short8*)&Ps[wv][row * 32 + ((quad ^ (l15 & 3)) * 8)];
      }
#pragma unroll
      for (int dt = 0; dt < 4; ++dt) {
        const int d = dt * 16 + l15;
        const int c = kc * 4 + quad;
        vf[dt] = *(const short8*)&Vt[d * 128 + ((c ^ (d & 7)) * 8)];
      }
#pragma unroll
      for (int mt = 0; mt < 4; ++mt)
#pragma unroll
        for (int dt = 0; dt < 4; ++dt)
          accy[mt][dt] = __builtin_amdgcn_mfma_f32_16x16x32_bf16(pf[mt], vf[dt],
                                                                 accy[mt][dt], 0, 0, 0);
    }
  }

  // ---- epilogue: y/l -> compact bf16 Y [16384][1024] ----
#pragma unroll
  for (int mt = 0; mt < 4; ++mt) {
#pragma unroll
    for (int reg = 0; reg < 4; ++reg) {
      const float rl = 1.f / l_[mt][reg];
      const int row = wv * 64 + mt * 16 + quad * 4 + reg;
      unsigned short* yp = Y + ((size_t)b * T_SEQ + t0 + row) * CDIM + h * 64;
#pragma unroll
      for (int dt = 0; dt < 4; ++dt)
        yp[dt * 16 + l15] = (unsigned short)f2bf(accy[mt][dt][reg] * rl);
    }
  }
}

// ---------------------------------------------------------------------------
// ws layout (bytes): [0,96M) qkv bf16 [16384][3072]; [96M,128M) x bf16;
// [128M,160M) y bf16; [160M,166M) W_inT bf16; [166M,168M) W_outT bf16;
// [168M,169M) rope table float2 [4096][32].
// ---------------------------------------------------------------------------
extern "C" void kernel_launch(void* const* d_in, const int* in_sizes, int n_in,
                              void* d_out, int out_size, void* d_ws, size_t ws_size,
                              hipStream_t stream) {
  const float* x     = (const float*)d_in[0];
  const float* W_in  = (const float*)d_in[1];
  const float* b_in  = (const float*)d_in[2];
  const float* W_out = (const float*)d_in[3];
  const float* b_out = (const float*)d_in[4];
  float* out = (float*)d_out;
  char* ws = (char*)d_ws;
  unsigned short* qkvb  = (unsigned short*)ws;
  unsigned short* Abf   = (unsigned short*)(ws + (96u << 20));
  unsigned short* Ybf   = (unsigned short*)(ws + (128u << 20));
  unsigned short* WinT  = (unsigned short*)(ws + (160u << 20));
  unsigned short* WoutT = (unsigned short*)(ws + (166u << 20));
  float2* ropetabp      = (float2*)(ws + (168u << 20));

  rope_tab<<<512, 256, 0, stream>>>(ropetabp);
  cvt_f32_bf16<<<8192, 256, 0, stream>>>(x, Abf);
  transpose_cvt<<<dim3(3072 / 32, 1024 / 32), 256, 0, stream>>>(W_in, WinT, 1024, 3072);
  transpose_cvt<<<dim3(1024 / 32, 1024 / 32), 256, 0, stream>>>(W_out, WoutT, 1024, 1024);
  gemm_bf16<<<dim3(3072 / 128, 16384 / 128), 256, 0, stream>>>(
      Abf, WinT, b_in, ropetabp, qkvb, 3 * CDIM, CDIM, 1);
  attn_mfma<<<dim3(T_SEQ / WIN, 16, 4), 256, 0, stream>>>(qkvb, Ybf);
  gemm_bf16<<<dim3(1024 / 128, 16384 / 128), 256, 0, stream>>>(
      Ybf, WoutT, b_out, nullptr, out, CDIM, CDIM, 0);
}

// Round 4
// 516.037 us; speedup vs baseline: 1.2727x; 1.2727x over previous
//
#include <hip/hip_runtime.h>
#include <math.h>

// (B,T,C)=(4,4096,1024), 16 heads x 64, window 256, rope base 1e4.
#define T_SEQ 4096
#define CDIM  1024
#define WIN   256

// log2(10000)/32 — inv_freq[pi] = 2^(-pi * ROPE_C)
#define ROPE_C 0.415241012f
// 0.125 * log2(e): softmax in exp2 domain
#define SCALE_LOG2E 0.1803368801f

typedef __attribute__((ext_vector_type(8))) short short8;
typedef __attribute__((ext_vector_type(4))) float float4v;

__device__ __forceinline__ unsigned int f2bf(float f) {
  unsigned int u = __float_as_uint(f);
  u += 0x7fffu + ((u >> 16) & 1u);
  return u >> 16;
}

// async global->LDS, 16B per lane. LDS dest must be linear (wave base + lane*16).
__device__ __forceinline__ void gload16(const unsigned short* g, unsigned short* l) {
  __builtin_amdgcn_global_load_lds(
      (__attribute__((address_space(1))) void*)g,
      (__attribute__((address_space(3))) void*)l, 16, 0, 0);
}

// ---------------------------------------------------------------------------
// RoPE table: tab[t*32+pi] = {cos(t*inv[pi]), sin(t*inv[pi])}, 4096x32, 1 MiB.
// ---------------------------------------------------------------------------
__global__ __launch_bounds__(256)
void rope_tab(float2* __restrict__ tab) {
  const int i = blockIdx.x * 256 + threadIdx.x;   // 0..131071
  const int tpos = i >> 5, pi = i & 31;
  const float ang = (float)tpos * exp2f(-(float)pi * ROPE_C);
  tab[i] = make_float2(cosf(ang), sinf(ang));
}

// ---------------------------------------------------------------------------
// Permuted bias: q/k cols de-interleaved within each 64-col head
// (even pair-components -> 0..31, odd -> 32..63). v cols identity.
// ---------------------------------------------------------------------------
__global__ __launch_bounds__(256)
void perm_bias(const float* __restrict__ b, float* __restrict__ pb) {
  const int n = blockIdx.x * 256 + threadIdx.x;   // 0..3071
  int np = n;
  if (n < 2 * CDIM) np = (n & ~63) | ((n & 1) * 32) | ((n & 63) >> 1);
  pb[np] = b[n];
}

// ---------------------------------------------------------------------------
// x fp32 -> bf16, 8 elems/thread.
// ---------------------------------------------------------------------------
__global__ __launch_bounds__(256)
void cvt_f32_bf16(const float* __restrict__ src, unsigned short* __restrict__ dst) {
  const long i = ((long)blockIdx.x * 256 + threadIdx.x) * 8;
  float4 u0 = *(const float4*)(src + i);
  float4 u1 = *(const float4*)(src + i + 4);
  uint4 pk;
  pk.x = f2bf(u0.x) | (f2bf(u0.y) << 16);
  pk.y = f2bf(u0.z) | (f2bf(u0.w) << 16);
  pk.z = f2bf(u1.x) | (f2bf(u1.y) << 16);
  pk.w = f2bf(u1.z) | (f2bf(u1.w) << 16);
  *(uint4*)(dst + i) = pk;
}

// ---------------------------------------------------------------------------
// W fp32 [K][N] row-major -> W^T bf16 [N][K] linear. permqk=1: de-interleave
// rope pairs within each head for cols<2048 (dot-products invariant since q
// and k share the permutation; makes rope lane-local in the GEMM epilogue).
// ---------------------------------------------------------------------------
__global__ __launch_bounds__(256)
void transpose_cvt(const float* __restrict__ W, unsigned short* __restrict__ dst,
                   int K, int N, int permqk) {
  __shared__ float tile[32][33];
  const int tid = threadIdx.x;
  const int ktile = blockIdx.y * 32, ntile = blockIdx.x * 32;
  const int kl = tid >> 3, nl4 = (tid & 7) * 4;
  float4 v = *(const float4*)&W[(size_t)(ktile + kl) * N + ntile + nl4];
  tile[nl4 + 0][kl] = v.x;
  tile[nl4 + 1][kl] = v.y;
  tile[nl4 + 2][kl] = v.z;
  tile[nl4 + 3][kl] = v.w;
  __syncthreads();
  const int nl = tid >> 3, kl4 = (tid & 7) * 4;
  uint2 pk;
  pk.x = f2bf(tile[nl][kl4 + 0]) | (f2bf(tile[nl][kl4 + 1]) << 16);
  pk.y = f2bf(tile[nl][kl4 + 2]) | (f2bf(tile[nl][kl4 + 3]) << 16);
  int n = ntile + nl;
  if (permqk && n < 2 * CDIM) n = (n & ~63) | ((n & 1) * 32) | ((n & 63) >> 1);
  long i = (long)n * K + ktile + kl4;
  *(uint2*)(dst + i) = pk;
}

// ---------------------------------------------------------------------------
// Pure-bf16 MFMA GEMM, m97 structure: C = A(bf16 [M][K]) @ Bt(bf16 [N][K])^T
// + bias. 128x128 block, 4 waves, 16x16x32 mfma, BK=32, LDS 16 KiB.
// VGPR is the controlling resource (R3 lesson: 104 VGPR -> 4 waves/SIMD
// cliff, -40%); min-waves hint guards >=5 waves/SIMD.
// mode=1: bf16 out; q/k cols get lane-local rope (permuted-pair layout:
// x1=acc[mt][nt], x2=acc[mt][nt+2] same lane; 1 table gather + 4 FMA,
// no shuffles, no trig). mode=0: fp32 out.
// ---------------------------------------------------------------------------
__global__ __launch_bounds__(256, 5)
void gemm_bf16(const unsigned short* __restrict__ A,
               const unsigned short* __restrict__ Bt,
               const float* __restrict__ bias,
               const float2* __restrict__ ropetab,
               void* __restrict__ Cp, int ldc, int K, int mode) {
  __shared__ unsigned short As[128 * 32];
  __shared__ unsigned short Bs[128 * 32];
  const int t = threadIdx.x;
  const int row0 = blockIdx.y * 128, col0 = blockIdx.x * 128;
  const int lane = t & 63, wave = t >> 6;
  const int wm = (wave >> 1) * 64, wn = (wave & 1) * 64;
  const int l15 = lane & 15, quad = lane >> 4;

  // staging map: thread t covers LDS elems [t*8, t*8+8) (+2048 for pass 1)
  // -> tile row sr = t>>2 (+64), LDS chunk t&3. Source chunk = (t&3)^((sr>>1)&3).
  const int sr = t >> 2;
  const int sc = (t & 3) ^ ((sr >> 1) & 3);
  const unsigned short* a0 = A + (size_t)(row0 + sr) * K + sc * 8;
  const unsigned short* b0 = Bt + (size_t)(col0 + sr) * K + sc * 8;
  unsigned short* la = &As[t * 8];
  unsigned short* lb = &Bs[t * 8];

  float4v acc[4][4];
#pragma unroll
  for (int i = 0; i < 4; ++i)
#pragma unroll
    for (int j = 0; j < 4; ++j) acc[i][j] = (float4v){0.f, 0.f, 0.f, 0.f};

  for (int k0 = 0; k0 < K; k0 += 32) {
    __syncthreads();                      // all waves done reading prev tile
    gload16(a0 + k0, la);
    gload16(a0 + (size_t)64 * K + k0, la + 2048);
    gload16(b0 + k0, lb);
    gload16(b0 + (size_t)64 * K + k0, lb + 2048);
    asm volatile("s_waitcnt vmcnt(0)" ::: "memory");
    __syncthreads();                      // tile ready for everyone

    short8 af[4], bfr[4];
#pragma unroll
    for (int mt = 0; mt < 4; ++mt) {
      const int r = wm + mt * 16 + l15;
      af[mt] = *(const short8*)&As[r * 32 + ((quad ^ ((r >> 1) & 3)) * 8)];
    }
#pragma unroll
    for (int nt = 0; nt < 4; ++nt) {
      const int r = wn + nt * 16 + l15;
      bfr[nt] = *(const short8*)&Bs[r * 32 + ((quad ^ ((r >> 1) & 3)) * 8)];
    }
#pragma unroll
    for (int mt = 0; mt < 4; ++mt)
#pragma unroll
      for (int nt = 0; nt < 4; ++nt)
        acc[mt][nt] = __builtin_amdgcn_mfma_f32_16x16x32_bf16(af[mt], bfr[nt],
                                                              acc[mt][nt], 0, 0, 0);
  }

  if (mode) {
    unsigned short* co = (unsigned short*)Cp;
    if (col0 < 2 * CDIM) {
      // ---- q/k block: lane-local rope via permuted-pair layout ----
#pragma unroll
      for (int ntp = 0; ntp < 2; ++ntp) {
        const int col1 = col0 + wn + ntp * 16 + l15;   // even component
        const float bb1 = bias[col1];
        const float bb2 = bias[col1 + 32];
        const int pi = ntp * 16 + l15;
#pragma unroll
        for (int mt = 0; mt < 4; ++mt) {
#pragma unroll
          for (int r = 0; r < 4; ++r) {
            const int row = row0 + wm + mt * 16 + quad * 4 + r;
            const float2 cs = ropetab[(size_t)(row & (T_SEQ - 1)) * 32 + pi];
            const float x1 = acc[mt][ntp][r] + bb1;
            const float x2 = acc[mt][ntp + 2][r] + bb2;
            const float y1 = x1 * cs.x - x2 * cs.y;
            const float y2 = x1 * cs.y + x2 * cs.x;
            const float y1p = __shfl_xor(y1, 1);
            const float y2p = __shfl_xor(y2, 1);
            if (!(l15 & 1)) {
              unsigned short* rp = co + (size_t)row * ldc + col1;
              *(unsigned int*)rp = f2bf(y1) | (f2bf(y1p) << 16);
              *(unsigned int*)(rp + 32) = f2bf(y2) | (f2bf(y2p) << 16);
            }
          }
        }
      }
    } else {
      // ---- v block: bias only ----
#pragma unroll
      for (int nt = 0; nt < 4; ++nt) {
        const int col = col0 + wn + nt * 16 + l15;
        const float bb = bias[col];
#pragma unroll
        for (int mt = 0; mt < 4; ++mt) {
#pragma unroll
          for (int r = 0; r < 4; ++r) {
            const int row = row0 + wm + mt * 16 + quad * 4 + r;
            const float v = acc[mt][nt][r] + bb;
            const float vp = __shfl_xor(v, 1);
            if (!(l15 & 1))
              *(unsigned int*)(co + (size_t)row * ldc + col) =
                  f2bf(v) | (f2bf(vp) << 16);
          }
        }
      }
    }
  } else {
    // ---- fp32 epilogue (output GEMM): direct stores ----
    float* co = (float*)Cp;
#pragma unroll
    for (int nt = 0; nt < 4; ++nt) {
      const int col = col0 + wn + nt * 16 + l15;
      const float bb = bias[col];
#pragma unroll
      for (int mt = 0; mt < 4; ++mt) {
#pragma unroll
        for (int r = 0; r < 4; ++r) {
          const int row = row0 + wm + mt * 16 + quad * 4 + r;
          co[(size_t)row * ldc + col] = acc[mt][nt][r] + bb;
        }
      }
    }
  }
}

// ---------------------------------------------------------------------------
// MFMA flash attention on bf16 qkv (q/k in permuted head layout — QK^T
// invariant). Y stores packed to 4B (was scalar 2B).
// ---------------------------------------------------------------------------
__global__ __launch_bounds__(256, 2)
void attn_mfma(const unsigned short* __restrict__ qkv, unsigned short* __restrict__ Y) {
  __shared__ unsigned short Ks[128 * 64];   // [key][d], 16 KiB
  __shared__ unsigned short Vt[64 * 128];   // [d][key], 16 KiB
  __shared__ unsigned short Ps[4][64 * 32]; // per-wave P chunk, 16 KiB

  const int w = blockIdx.x, h = blockIdx.y, b = blockIdx.z;
  const int t = threadIdx.x;
  const int lane = t & 63, wv = t >> 6;
  const int l15 = lane & 15, quad = lane >> 4;
  const int t0 = w * WIN;
  const size_t base = ((size_t)b * T_SEQ + t0) * 3072;

  // ---- Q A-frags: direct bf16 16B loads ----
  short8 qf[4][2];
#pragma unroll
  for (int mt = 0; mt < 4; ++mt) {
    const unsigned short* qp = qkv + base + (size_t)(wv * 64 + mt * 16 + l15) * 3072 + h * 64;
#pragma unroll
    for (int ks = 0; ks < 2; ++ks)
      qf[mt][ks] = *(const short8*)(qp + ks * 32 + quad * 8);
  }

  float4v accy[4][4];
#pragma unroll
  for (int i = 0; i < 4; ++i)
#pragma unroll
    for (int j = 0; j < 4; ++j) accy[i][j] = (float4v){0.f, 0.f, 0.f, 0.f};
  float m_[4][4], l_[4][4];
#pragma unroll
  for (int i = 0; i < 4; ++i)
#pragma unroll
    for (int j = 0; j < 4; ++j) { m_[i][j] = -3.0e38f; l_[i][j] = 0.f; }

  for (int half = 0; half < 2; ++half) {
    if (half) __syncthreads();   // all waves done reading previous half
    // ---- stage K half via global_load_lds ----
    {
      const int kr = t >> 3, kc = t & 7;
      const unsigned short* kp = qkv + base + (size_t)(half * 128 + kr) * 3072 + 1024 +
                                 h * 64 + ((kc ^ (kr & 7)) * 8);
      unsigned short* lp = &Ks[t * 8];
#pragma unroll
      for (int p = 0; p < 4; ++p)
        gload16(kp + (size_t)p * 32 * 3072, lp + p * 2048);
    }
    // ---- stage V^T half ----
    {
      const int kpair = 2 * (t & 63);
      const int d0 = (t >> 6) * 16;
      const unsigned short* v0 = qkv + base + (size_t)(half * 128 + kpair) * 3072 + 2048 +
                                 h * 64 + d0;
      const unsigned short* v1 = v0 + 3072;
      short8 a0[2], a1[2];
#pragma unroll
      for (int j = 0; j < 2; ++j) {
        a0[j] = *(const short8*)(v0 + j * 8);
        a1[j] = *(const short8*)(v1 + j * 8);
      }
      const int c = kpair >> 3;
#pragma unroll
      for (int j = 0; j < 2; ++j)
#pragma unroll
        for (int e = 0; e < 8; ++e) {
          const int d = d0 + 8 * j + e;
          const unsigned int pk = (unsigned int)(unsigned short)a0[j][e] |
                                  ((unsigned int)(unsigned short)a1[j][e] << 16);
          *(unsigned int*)&Vt[d * 128 + ((c ^ (d & 7)) * 8) + (kpair & 7)] = pk;
        }
    }
    asm volatile("s_waitcnt vmcnt(0)" ::: "memory");
    __syncthreads();

    for (int kc = 0; kc < 4; ++kc) {   // 32-key chunks within half
      short8 kf[2][2];
#pragma unroll
      for (int nt = 0; nt < 2; ++nt)
#pragma unroll
        for (int ks = 0; ks < 2; ++ks) {
          const int r = kc * 32 + nt * 16 + l15;
          const int c = ks * 4 + quad;
          kf[nt][ks] = *(const short8*)&Ks[r * 64 + ((c ^ (l15 & 7)) * 8)];
        }
      float4v s_[4][2];
#pragma unroll
      for (int mt = 0; mt < 4; ++mt)
#pragma unroll
        for (int nt = 0; nt < 2; ++nt) {
          s_[mt][nt] = __builtin_amdgcn_mfma_f32_16x16x32_bf16(
              qf[mt][0], kf[nt][0], (float4v){0.f, 0.f, 0.f, 0.f}, 0, 0, 0);
          s_[mt][nt] = __builtin_amdgcn_mfma_f32_16x16x32_bf16(
              qf[mt][1], kf[nt][1], s_[mt][nt], 0, 0, 0);
        }
      // ---- online softmax + P write ----
#pragma unroll
      for (int mt = 0; mt < 4; ++mt) {
#pragma unroll
        for (int reg = 0; reg < 4; ++reg) {
          float s0 = s_[mt][0][reg] * SCALE_LOG2E;
          float s1 = s_[mt][1][reg] * SCALE_LOG2E;
          float mx = fmaxf(s0, s1);
          mx = fmaxf(mx, __shfl_xor(mx, 1));
          mx = fmaxf(mx, __shfl_xor(mx, 2));
          mx = fmaxf(mx, __shfl_xor(mx, 4));
          mx = fmaxf(mx, __shfl_xor(mx, 8));
          const float mn = fmaxf(m_[mt][reg], mx);
          const float al = exp2f(m_[mt][reg] - mn);
          const float p0 = exp2f(s0 - mn);
          const float p1 = exp2f(s1 - mn);
          float ps = p0 + p1;
          ps += __shfl_xor(ps, 1);
          ps += __shfl_xor(ps, 2);
          ps += __shfl_xor(ps, 4);
          ps += __shfl_xor(ps, 8);
          l_[mt][reg] = l_[mt][reg] * al + ps;
          m_[mt][reg] = mn;
#pragma unroll
          for (int dt = 0; dt < 4; ++dt) accy[mt][dt][reg] *= al;
          const float q0 = __shfl_xor(p0, 1);
          const float q1 = __shfl_xor(p1, 1);
          const unsigned int w0 = f2bf(p0) | (f2bf(q0) << 16);
          const unsigned int w1 = f2bf(p1) | (f2bf(q1) << 16);
          if (!(l15 & 1)) {
            const int row = mt * 16 + quad * 4 + reg;
            const int ca = (0 + (l15 >> 3)) ^ (row & 3);
            const int cb = (2 + (l15 >> 3)) ^ (row & 3);
            *(unsigned int*)&Ps[wv][row * 32 + ca * 8 + (l15 & 7)] = w0;
            *(unsigned int*)&Ps[wv][row * 32 + cb * 8 + (l15 & 7)] = w1;
          }
        }
      }
      // ---- P A-frags + V^T B-frags, y += P @ V ----
      short8 pf[4], vf[4];
#pragma unroll
      for (int mt = 0; mt < 4; ++mt) {
        const int row = mt * 16 + l15;
        pf[mt] = *(const short8*)&Ps[wv][row * 32 + ((quad ^ (l15 & 3)) * 8)];
      }
#pragma unroll
      for (int dt = 0; dt < 4; ++dt) {
        const int d = dt * 16 + l15;
        const int c = kc * 4 + quad;
        vf[dt] = *(const short8*)&Vt[d * 128 + ((c ^ (d & 7)) * 8)];
      }
#pragma unroll
      for (int mt = 0; mt < 4; ++mt)
#pragma unroll
        for (int dt = 0; dt < 4; ++dt)
          accy[mt][dt] = __builtin_amdgcn_mfma_f32_16x16x32_bf16(pf[mt], vf[dt],
                                                                 accy[mt][dt], 0, 0, 0);
    }
  }

  // ---- epilogue: y/l -> compact bf16 Y [16384][1024], 4B packed stores ----
#pragma unroll
  for (int mt = 0; mt < 4; ++mt) {
#pragma unroll
    for (int reg = 0; reg < 4; ++reg) {
      const float rl = 1.f / l_[mt][reg];
      const int row = wv * 64 + mt * 16 + quad * 4 + reg;
      unsigned short* yp = Y + ((size_t)b * T_SEQ + t0 + row) * CDIM + h * 64;
#pragma unroll
      for (int dt = 0; dt < 4; ++dt) {
        const float y = accy[mt][dt][reg] * rl;
        const float ypart = __shfl_xor(y, 1);
        if (!(l15 & 1))
          *(unsigned int*)(yp + dt * 16 + l15) = f2bf(y) | (f2bf(ypart) << 16);
      }
    }
  }
}

// ---------------------------------------------------------------------------
// ws layout (bytes): [0,96M) qkv bf16 [16384][3072]; [96M,128M) x bf16;
// [128M,160M) y bf16; [160M,166M) W_inT bf16 (permuted); [166M,168M) W_outT;
// [168M,169M) rope table float2 [4096][32]; [169M,+12K) permuted bias.
// ---------------------------------------------------------------------------
extern "C" void kernel_launch(void* const* d_in, const int* in_sizes, int n_in,
                              void* d_out, int out_size, void* d_ws, size_t ws_size,
                              hipStream_t stream) {
  const float* x     = (const float*)d_in[0];
  const float* W_in  = (const float*)d_in[1];
  const float* b_in  = (const float*)d_in[2];
  const float* W_out = (const float*)d_in[3];
  const float* b_out = (const float*)d_in[4];
  float* out = (float*)d_out;
  char* ws = (char*)d_ws;
  unsigned short* qkvb  = (unsigned short*)ws;
  unsigned short* Abf   = (unsigned short*)(ws + (96u << 20));
  unsigned short* Ybf   = (unsigned short*)(ws + (128u << 20));
  unsigned short* WinT  = (unsigned short*)(ws + (160u << 20));
  unsigned short* WoutT = (unsigned short*)(ws + (166u << 20));
  float2* ropetabp      = (float2*)(ws + (168u << 20));
  float* pbias          = (float*)(ws + (169u << 20));

  rope_tab<<<512, 256, 0, stream>>>(ropetabp);
  perm_bias<<<12, 256, 0, stream>>>(b_in, pbias);
  cvt_f32_bf16<<<8192, 256, 0, stream>>>(x, Abf);
  transpose_cvt<<<dim3(3072 / 32, 1024 / 32), 256, 0, stream>>>(W_in, WinT, 1024, 3072, 1);
  transpose_cvt<<<dim3(1024 / 32, 1024 / 32), 256, 0, stream>>>(W_out, WoutT, 1024, 1024, 0);
  gemm_bf16<<<dim3(3072 / 128, 16384 / 128), 256, 0, stream>>>(
      Abf, WinT, pbias, ropetabp, qkvb, 3 * CDIM, CDIM, 1);
  attn_mfma<<<dim3(T_SEQ / WIN, 16, 4), 256, 0, stream>>>(qkvb, Ybf);
  gemm_bf16<<<dim3(1024 / 128, 16384 / 128), 256, 0, stream>>>(
      Ybf, WoutT, b_out, nullptr, out, CDIM, CDIM, 0);
}

// Round 5
// 443.308 us; speedup vs baseline: 1.4816x; 1.1641x over previous
//
#include <hip/hip_runtime.h>
#include <math.h>

// (B,T,C)=(4,4096,1024), 16 heads x 64, window 256, rope base 1e4.
#define T_SEQ 4096
#define CDIM  1024
#define WIN   256

// log2(10000)/32 — inv_freq[pi] = 2^(-pi * ROPE_C)
#define ROPE_C 0.415241012f
// 0.125 * log2(e): softmax in exp2 domain
#define SCALE_LOG2E 0.1803368801f

typedef __attribute__((ext_vector_type(8))) short short8;
typedef __attribute__((ext_vector_type(4))) float float4v;

__device__ __forceinline__ unsigned int f2bf(float f) {
  unsigned int u = __float_as_uint(f);
  u += 0x7fffu + ((u >> 16) & 1u);
  return u >> 16;
}

// async global->LDS, 16B per lane. LDS dest must be linear (wave base + lane*16).
__device__ __forceinline__ void gload16(const unsigned short* g, unsigned short* l) {
  __builtin_amdgcn_global_load_lds(
      (__attribute__((address_space(1))) void*)g,
      (__attribute__((address_space(3))) void*)l, 16, 0, 0);
}

// ---------------------------------------------------------------------------
// RoPE table: tab[t*32+pi] = {cos(t*inv[pi]), sin(t*inv[pi])}, 4096x32, 1 MiB.
// ---------------------------------------------------------------------------
__global__ __launch_bounds__(256)
void rope_tab(float2* __restrict__ tab) {
  const int i = blockIdx.x * 256 + threadIdx.x;   // 0..131071
  const int tpos = i >> 5, pi = i & 31;
  const float ang = (float)tpos * exp2f(-(float)pi * ROPE_C);
  tab[i] = make_float2(cosf(ang), sinf(ang));
}

// ---------------------------------------------------------------------------
// Permuted bias: q/k cols de-interleaved within each 64-col head
// (even pair-components -> 0..31, odd -> 32..63). v cols identity.
// ---------------------------------------------------------------------------
__global__ __launch_bounds__(256)
void perm_bias(const float* __restrict__ b, float* __restrict__ pb) {
  const int n = blockIdx.x * 256 + threadIdx.x;   // 0..3071
  int np = n;
  if (n < 2 * CDIM) np = (n & ~63) | ((n & 1) * 32) | ((n & 63) >> 1);
  pb[np] = b[n];
}

// ---------------------------------------------------------------------------
// x fp32 -> bf16, 8 elems/thread.
// ---------------------------------------------------------------------------
__global__ __launch_bounds__(256)
void cvt_f32_bf16(const float* __restrict__ src, unsigned short* __restrict__ dst) {
  const long i = ((long)blockIdx.x * 256 + threadIdx.x) * 8;
  float4 u0 = *(const float4*)(src + i);
  float4 u1 = *(const float4*)(src + i + 4);
  uint4 pk;
  pk.x = f2bf(u0.x) | (f2bf(u0.y) << 16);
  pk.y = f2bf(u0.z) | (f2bf(u0.w) << 16);
  pk.z = f2bf(u1.x) | (f2bf(u1.y) << 16);
  pk.w = f2bf(u1.z) | (f2bf(u1.w) << 16);
  *(uint4*)(dst + i) = pk;
}

// ---------------------------------------------------------------------------
// W fp32 [K][N] row-major -> W^T bf16 [N][K] linear. permqk=1: de-interleave
// rope pairs within each head for cols<2048 (dot-products invariant since q
// and k share the permutation; makes rope lane-local in the GEMM epilogue).
// ---------------------------------------------------------------------------
__global__ __launch_bounds__(256)
void transpose_cvt(const float* __restrict__ W, unsigned short* __restrict__ dst,
                   int K, int N, int permqk) {
  __shared__ float tile[32][33];
  const int tid = threadIdx.x;
  const int ktile = blockIdx.y * 32, ntile = blockIdx.x * 32;
  const int kl = tid >> 3, nl4 = (tid & 7) * 4;
  float4 v = *(const float4*)&W[(size_t)(ktile + kl) * N + ntile + nl4];
  tile[nl4 + 0][kl] = v.x;
  tile[nl4 + 1][kl] = v.y;
  tile[nl4 + 2][kl] = v.z;
  tile[nl4 + 3][kl] = v.w;
  __syncthreads();
  const int nl = tid >> 3, kl4 = (tid & 7) * 4;
  uint2 pk;
  pk.x = f2bf(tile[nl][kl4 + 0]) | (f2bf(tile[nl][kl4 + 1]) << 16);
  pk.y = f2bf(tile[nl][kl4 + 2]) | (f2bf(tile[nl][kl4 + 3]) << 16);
  int n = ntile + nl;
  if (permqk && n < 2 * CDIM) n = (n & ~63) | ((n & 1) * 32) | ((n & 63) >> 1);
  long i = (long)n * K + ktile + kl4;
  *(uint2*)(dst + i) = pk;
}

// ---------------------------------------------------------------------------
// Pure-bf16 MFMA GEMM, m97 structure: C = A(bf16 [M][K]) @ Bt(bf16 [N][K])^T
// + bias. 128x128 block, 4 waves, 16x16x32 mfma, BK=32, LDS 16 KiB,
// VGPR capped via min-waves=5 (R3 lesson: 104 VGPR -> -40% cliff).
// 1D grid + XCD-chunked swizzle (T1): consecutive panel blocks share an
// XCD L2 -> A-panel fetched once per XCD, not 8x (R4: FETCH 220MB vs 38
// ideal, matching A x 8 XCD re-fetch).
// Epilogues reordered row-outer so all segments of a row's 128B stretch
// issue back-to-back (write-combine; R4 WRITE 204MB vs 96 ideal).
// mode=1: bf16 out, lane-local rope (permuted-pair layout). mode=0: fp32.
// ---------------------------------------------------------------------------
__global__ __launch_bounds__(256, 5)
void gemm_bf16(const unsigned short* __restrict__ A,
               const unsigned short* __restrict__ Bt,
               const float* __restrict__ bias,
               const float2* __restrict__ ropetab,
               void* __restrict__ Cp, int ldc, int K, int mode, int nbx) {
  __shared__ unsigned short As[128 * 32];
  __shared__ unsigned short Bs[128 * 32];
  const int t = threadIdx.x;
  // XCD-chunked bijective swizzle (nwg % 8 == 0 for both call sites)
  const int nwg = gridDim.x;
  const int cpx = nwg >> 3;
  const int wg = blockIdx.x;
  const int swz = (wg & 7) * cpx + (wg >> 3);
  const int row0 = (swz / nbx) * 128, col0 = (swz % nbx) * 128;
  const int lane = t & 63, wave = t >> 6;
  const int wm = (wave >> 1) * 64, wn = (wave & 1) * 64;
  const int l15 = lane & 15, quad = lane >> 4;

  // staging map: thread t covers LDS elems [t*8, t*8+8) (+2048 for pass 1)
  // -> tile row sr = t>>2 (+64), LDS chunk t&3. Source chunk = (t&3)^((sr>>1)&3).
  const int sr = t >> 2;
  const int sc = (t & 3) ^ ((sr >> 1) & 3);
  const unsigned short* a0 = A + (size_t)(row0 + sr) * K + sc * 8;
  const unsigned short* b0 = Bt + (size_t)(col0 + sr) * K + sc * 8;
  unsigned short* la = &As[t * 8];
  unsigned short* lb = &Bs[t * 8];

  float4v acc[4][4];
#pragma unroll
  for (int i = 0; i < 4; ++i)
#pragma unroll
    for (int j = 0; j < 4; ++j) acc[i][j] = (float4v){0.f, 0.f, 0.f, 0.f};

  for (int k0 = 0; k0 < K; k0 += 32) {
    __syncthreads();                      // all waves done reading prev tile
    gload16(a0 + k0, la);
    gload16(a0 + (size_t)64 * K + k0, la + 2048);
    gload16(b0 + k0, lb);
    gload16(b0 + (size_t)64 * K + k0, lb + 2048);
    asm volatile("s_waitcnt vmcnt(0)" ::: "memory");
    __syncthreads();                      // tile ready for everyone

    short8 af[4], bfr[4];
#pragma unroll
    for (int mt = 0; mt < 4; ++mt) {
      const int r = wm + mt * 16 + l15;
      af[mt] = *(const short8*)&As[r * 32 + ((quad ^ ((r >> 1) & 3)) * 8)];
    }
#pragma unroll
    for (int nt = 0; nt < 4; ++nt) {
      const int r = wn + nt * 16 + l15;
      bfr[nt] = *(const short8*)&Bs[r * 32 + ((quad ^ ((r >> 1) & 3)) * 8)];
    }
#pragma unroll
    for (int mt = 0; mt < 4; ++mt)
#pragma unroll
      for (int nt = 0; nt < 4; ++nt)
        acc[mt][nt] = __builtin_amdgcn_mfma_f32_16x16x32_bf16(af[mt], bfr[nt],
                                                              acc[mt][nt], 0, 0, 0);
  }

  if (mode) {
    unsigned short* co = (unsigned short*)Cp;
    if (col0 < 2 * CDIM) {
      // ---- q/k block: lane-local rope; row-outer store order ----
      float bb1[2], bb2[2];
#pragma unroll
      for (int ntp = 0; ntp < 2; ++ntp) {
        bb1[ntp] = bias[col0 + wn + ntp * 16 + l15];
        bb2[ntp] = bias[col0 + wn + ntp * 16 + l15 + 32];
      }
#pragma unroll
      for (int mt = 0; mt < 4; ++mt) {
#pragma unroll
        for (int r = 0; r < 4; ++r) {
          const int row = row0 + wm + mt * 16 + quad * 4 + r;
          const float2* tb = &ropetab[(size_t)(row & (T_SEQ - 1)) * 32];
          unsigned short* rp0 = co + (size_t)row * ldc + col0 + wn;
#pragma unroll
          for (int ntp = 0; ntp < 2; ++ntp) {
            const float2 cs = tb[ntp * 16 + l15];
            const float x1 = acc[mt][ntp][r] + bb1[ntp];
            const float x2 = acc[mt][ntp + 2][r] + bb2[ntp];
            const float y1 = x1 * cs.x - x2 * cs.y;
            const float y2 = x1 * cs.y + x2 * cs.x;
            const float y1p = __shfl_xor(y1, 1);
            const float y2p = __shfl_xor(y2, 1);
            if (!(l15 & 1)) {
              *(unsigned int*)(rp0 + ntp * 16 + l15) = f2bf(y1) | (f2bf(y1p) << 16);
              *(unsigned int*)(rp0 + ntp * 16 + l15 + 32) = f2bf(y2) | (f2bf(y2p) << 16);
            }
          }
        }
      }
    } else {
      // ---- v block: bias only; row-outer store order ----
      float bb[4];
#pragma unroll
      for (int nt = 0; nt < 4; ++nt) bb[nt] = bias[col0 + wn + nt * 16 + l15];
#pragma unroll
      for (int mt = 0; mt < 4; ++mt) {
#pragma unroll
        for (int r = 0; r < 4; ++r) {
          const int row = row0 + wm + mt * 16 + quad * 4 + r;
          unsigned short* rp0 = co + (size_t)row * ldc + col0 + wn;
#pragma unroll
          for (int nt = 0; nt < 4; ++nt) {
            const float v = acc[mt][nt][r] + bb[nt];
            const float vp = __shfl_xor(v, 1);
            if (!(l15 & 1))
              *(unsigned int*)(rp0 + nt * 16 + l15) = f2bf(v) | (f2bf(vp) << 16);
          }
        }
      }
    }
  } else {
    // ---- fp32 epilogue (output GEMM): row-outer, 256B contiguous per row ----
    float* co = (float*)Cp;
    float bb[4];
#pragma unroll
    for (int nt = 0; nt < 4; ++nt) bb[nt] = bias[col0 + wn + nt * 16 + l15];
#pragma unroll
    for (int mt = 0; mt < 4; ++mt) {
#pragma unroll
      for (int r = 0; r < 4; ++r) {
        const int row = row0 + wm + mt * 16 + quad * 4 + r;
        float* rp0 = co + (size_t)row * ldc + col0 + wn;
#pragma unroll
        for (int nt = 0; nt < 4; ++nt)
          rp0[nt * 16 + l15] = acc[mt][nt][r] + bb[nt];
      }
    }
  }
}

// ---------------------------------------------------------------------------
// MFMA flash attention on bf16 qkv (q/k in permuted head layout — QK^T
// invariant). Y stores packed to 4B.
// ---------------------------------------------------------------------------
__global__ __launch_bounds__(256, 2)
void attn_mfma(const unsigned short* __restrict__ qkv, unsigned short* __restrict__ Y) {
  __shared__ unsigned short Ks[128 * 64];   // [key][d], 16 KiB
  __shared__ unsigned short Vt[64 * 128];   // [d][key], 16 KiB
  __shared__ unsigned short Ps[4][64 * 32]; // per-wave P chunk, 16 KiB

  const int w = blockIdx.x, h = blockIdx.y, b = blockIdx.z;
  const int t = threadIdx.x;
  const int lane = t & 63, wv = t >> 6;
  const int l15 = lane & 15, quad = lane >> 4;
  const int t0 = w * WIN;
  const size_t base = ((size_t)b * T_SEQ + t0) * 3072;

  // ---- Q A-frags: direct bf16 16B loads ----
  short8 qf[4][2];
#pragma unroll
  for (int mt = 0; mt < 4; ++mt) {
    const unsigned short* qp = qkv + base + (size_t)(wv * 64 + mt * 16 + l15) * 3072 + h * 64;
#pragma unroll
    for (int ks = 0; ks < 2; ++ks)
      qf[mt][ks] = *(const short8*)(qp + ks * 32 + quad * 8);
  }

  float4v accy[4][4];
#pragma unroll
  for (int i = 0; i < 4; ++i)
#pragma unroll
    for (int j = 0; j < 4; ++j) accy[i][j] = (float4v){0.f, 0.f, 0.f, 0.f};
  float m_[4][4], l_[4][4];
#pragma unroll
  for (int i = 0; i < 4; ++i)
#pragma unroll
    for (int j = 0; j < 4; ++j) { m_[i][j] = -3.0e38f; l_[i][j] = 0.f; }

  for (int half = 0; half < 2; ++half) {
    if (half) __syncthreads();   // all waves done reading previous half
    // ---- stage K half via global_load_lds ----
    {
      const int kr = t >> 3, kc = t & 7;
      const unsigned short* kp = qkv + base + (size_t)(half * 128 + kr) * 3072 + 1024 +
                                 h * 64 + ((kc ^ (kr & 7)) * 8);
      unsigned short* lp = &Ks[t * 8];
#pragma unroll
      for (int p = 0; p < 4; ++p)
        gload16(kp + (size_t)p * 32 * 3072, lp + p * 2048);
    }
    // ---- stage V^T half ----
    {
      const int kpair = 2 * (t & 63);
      const int d0 = (t >> 6) * 16;
      const unsigned short* v0 = qkv + base + (size_t)(half * 128 + kpair) * 3072 + 2048 +
                                 h * 64 + d0;
      const unsigned short* v1 = v0 + 3072;
      short8 a0[2], a1[2];
#pragma unroll
      for (int j = 0; j < 2; ++j) {
        a0[j] = *(const short8*)(v0 + j * 8);
        a1[j] = *(const short8*)(v1 + j * 8);
      }
      const int c = kpair >> 3;
#pragma unroll
      for (int j = 0; j < 2; ++j)
#pragma unroll
        for (int e = 0; e < 8; ++e) {
          const int d = d0 + 8 * j + e;
          const unsigned int pk = (unsigned int)(unsigned short)a0[j][e] |
                                  ((unsigned int)(unsigned short)a1[j][e] << 16);
          *(unsigned int*)&Vt[d * 128 + ((c ^ (d & 7)) * 8) + (kpair & 7)] = pk;
        }
    }
    asm volatile("s_waitcnt vmcnt(0)" ::: "memory");
    __syncthreads();

    for (int kc = 0; kc < 4; ++kc) {   // 32-key chunks within half
      short8 kf[2][2];
#pragma unroll
      for (int nt = 0; nt < 2; ++nt)
#pragma unroll
        for (int ks = 0; ks < 2; ++ks) {
          const int r = kc * 32 + nt * 16 + l15;
          const int c = ks * 4 + quad;
          kf[nt][ks] = *(const short8*)&Ks[r * 64 + ((c ^ (l15 & 7)) * 8)];
        }
      float4v s_[4][2];
#pragma unroll
      for (int mt = 0; mt < 4; ++mt)
#pragma unroll
        for (int nt = 0; nt < 2; ++nt) {
          s_[mt][nt] = __builtin_amdgcn_mfma_f32_16x16x32_bf16(
              qf[mt][0], kf[nt][0], (float4v){0.f, 0.f, 0.f, 0.f}, 0, 0, 0);
          s_[mt][nt] = __builtin_amdgcn_mfma_f32_16x16x32_bf16(
              qf[mt][1], kf[nt][1], s_[mt][nt], 0, 0, 0);
        }
      // ---- online softmax + P write ----
#pragma unroll
      for (int mt = 0; mt < 4; ++mt) {
#pragma unroll
        for (int reg = 0; reg < 4; ++reg) {
          float s0 = s_[mt][0][reg] * SCALE_LOG2E;
          float s1 = s_[mt][1][reg] * SCALE_LOG2E;
          float mx = fmaxf(s0, s1);
          mx = fmaxf(mx, __shfl_xor(mx, 1));
          mx = fmaxf(mx, __shfl_xor(mx, 2));
          mx = fmaxf(mx, __shfl_xor(mx, 4));
          mx = fmaxf(mx, __shfl_xor(mx, 8));
          const float mn = fmaxf(m_[mt][reg], mx);
          const float al = exp2f(m_[mt][reg] - mn);
          const float p0 = exp2f(s0 - mn);
          const float p1 = exp2f(s1 - mn);
          float ps = p0 + p1;
          ps += __shfl_xor(ps, 1);
          ps += __shfl_xor(ps, 2);
          ps += __shfl_xor(ps, 4);
          ps += __shfl_xor(ps, 8);
          l_[mt][reg] = l_[mt][reg] * al + ps;
          m_[mt][reg] = mn;
#pragma unroll
          for (int dt = 0; dt < 4; ++dt) accy[mt][dt][reg] *= al;
          const float q0 = __shfl_xor(p0, 1);
          const float q1 = __shfl_xor(p1, 1);
          const unsigned int w0 = f2bf(p0) | (f2bf(q0) << 16);
          const unsigned int w1 = f2bf(p1) | (f2bf(q1) << 16);
          if (!(l15 & 1)) {
            const int row = mt * 16 + quad * 4 + reg;
            const int ca = (0 + (l15 >> 3)) ^ (row & 3);
            const int cb = (2 + (l15 >> 3)) ^ (row & 3);
            *(unsigned int*)&Ps[wv][row * 32 + ca * 8 + (l15 & 7)] = w0;
            *(unsigned int*)&Ps[wv][row * 32 + cb * 8 + (l15 & 7)] = w1;
          }
        }
      }
      // ---- P A-frags + V^T B-frags, y += P @ V ----
      short8 pf[4], vf[4];
#pragma unroll
      for (int mt = 0; mt < 4; ++mt) {
        const int row = mt * 16 + l15;
        pf[mt] = *(const short8*)&Ps[wv][row * 32 + ((quad ^ (l15 & 3)) * 8)];
      }
#pragma unroll
      for (int dt = 0; dt < 4; ++dt) {
        const int d = dt * 16 + l15;
        const int c = kc * 4 + quad;
        vf[dt] = *(const short8*)&Vt[d * 128 + ((c ^ (d & 7)) * 8)];
      }
#pragma unroll
      for (int mt = 0; mt < 4; ++mt)
#pragma unroll
        for (int dt = 0; dt < 4; ++dt)
          accy[mt][dt] = __builtin_amdgcn_mfma_f32_16x16x32_bf16(pf[mt], vf[dt],
                                                                 accy[mt][dt], 0, 0, 0);
    }
  }

  // ---- epilogue: y/l -> compact bf16 Y [16384][1024], 4B packed stores ----
#pragma unroll
  for (int mt = 0; mt < 4; ++mt) {
#pragma unroll
    for (int reg = 0; reg < 4; ++reg) {
      const float rl = 1.f / l_[mt][reg];
      const int row = wv * 64 + mt * 16 + quad * 4 + reg;
      unsigned short* yp = Y + ((size_t)b * T_SEQ + t0 + row) * CDIM + h * 64;
#pragma unroll
      for (int dt = 0; dt < 4; ++dt) {
        const float y = accy[mt][dt][reg] * rl;
        const float ypart = __shfl_xor(y, 1);
        if (!(l15 & 1))
          *(unsigned int*)(yp + dt * 16 + l15) = f2bf(y) | (f2bf(ypart) << 16);
      }
    }
  }
}

// ---------------------------------------------------------------------------
// ws layout (bytes): [0,96M) qkv bf16 [16384][3072]; [96M,128M) x bf16;
// [128M,160M) y bf16; [160M,166M) W_inT bf16 (permuted); [166M,168M) W_outT;
// [168M,169M) rope table float2 [4096][32]; [169M,+12K) permuted bias.
// ---------------------------------------------------------------------------
extern "C" void kernel_launch(void* const* d_in, const int* in_sizes, int n_in,
                              void* d_out, int out_size, void* d_ws, size_t ws_size,
                              hipStream_t stream) {
  const float* x     = (const float*)d_in[0];
  const float* W_in  = (const float*)d_in[1];
  const float* b_in  = (const float*)d_in[2];
  const float* W_out = (const float*)d_in[3];
  const float* b_out = (const float*)d_in[4];
  float* out = (float*)d_out;
  char* ws = (char*)d_ws;
  unsigned short* qkvb  = (unsigned short*)ws;
  unsigned short* Abf   = (unsigned short*)(ws + (96u << 20));
  unsigned short* Ybf   = (unsigned short*)(ws + (128u << 20));
  unsigned short* WinT  = (unsigned short*)(ws + (160u << 20));
  unsigned short* WoutT = (unsigned short*)(ws + (166u << 20));
  float2* ropetabp      = (float2*)(ws + (168u << 20));
  float* pbias          = (float*)(ws + (169u << 20));

  rope_tab<<<512, 256, 0, stream>>>(ropetabp);
  perm_bias<<<12, 256, 0, stream>>>(b_in, pbias);
  cvt_f32_bf16<<<8192, 256, 0, stream>>>(x, Abf);
  transpose_cvt<<<dim3(3072 / 32, 1024 / 32), 256, 0, stream>>>(W_in, WinT, 1024, 3072, 1);
  transpose_cvt<<<dim3(1024 / 32, 1024 / 32), 256, 0, stream>>>(W_out, WoutT, 1024, 1024, 0);
  gemm_bf16<<<dim3(24 * 128), 256, 0, stream>>>(
      Abf, WinT, pbias, ropetabp, qkvb, 3 * CDIM, CDIM, 1, 24);
  attn_mfma<<<dim3(T_SEQ / WIN, 16, 4), 256, 0, stream>>>(qkvb, Ybf);
  gemm_bf16<<<dim3(8 * 128), 256, 0, stream>>>(
      Ybf, WoutT, b_out, nullptr, out, CDIM, CDIM, 0, 8);
}